// Round 3
// baseline (43137.878 us; speedup 1.0000x reference)
//
#include <hip/hip_runtime.h>
#include <hip/hip_bf16.h>
#include <stdint.h>

#define BB 512
#define NN 200
#define TT 200
#define MM 20
#define H1N 128
#define MEN 32
#define DIN 128
#define H2N 256
#define JDN 256
#define AHN 256

typedef float f4v __attribute__((ext_vector_type(4)));

// ---------------- threefry2x32 (JAX-exact) ----------------
__device__ __forceinline__ void tf2x32(uint32_t k0, uint32_t k1,
                                       uint32_t x0, uint32_t x1,
                                       uint32_t& o0, uint32_t& o1) {
  uint32_t ks2 = k0 ^ k1 ^ 0x1BD11BDAu;
  x0 += k0; x1 += k1;
#define TF_RND(R) { x0 += x1; x1 = (x1 << (R)) | (x1 >> (32 - (R))); x1 ^= x0; }
  TF_RND(13) TF_RND(15) TF_RND(26) TF_RND(6)   x0 += k1;  x1 += ks2 + 1u;
  TF_RND(17) TF_RND(29) TF_RND(16) TF_RND(24)  x0 += ks2; x1 += k0 + 2u;
  TF_RND(13) TF_RND(15) TF_RND(26) TF_RND(6)   x0 += k0;  x1 += k1 + 3u;
  TF_RND(17) TF_RND(29) TF_RND(16) TF_RND(24)  x0 += k1;  x1 += ks2 + 4u;
  TF_RND(13) TF_RND(15) TF_RND(26) TF_RND(6)   x0 += ks2; x1 += k0 + 5u;
#undef TF_RND
  o0 = x0; o1 = x1;
}

// ---------------- small utility kernels ----------------
__global__ void k_transpose(const float* __restrict__ in, float* __restrict__ out,
                            int R, int C) {
  int idx = blockIdx.x * 256 + threadIdx.x;
  if (idx < R * C) { int r = idx / C, c = idx - r * C; out[c * R + r] = in[idx]; }
}

// Wc2[k*256+o]: k<128 -> w2ih[o*128+k]; k>=128 -> w2hh[o*256+(k-128)]
__global__ void k_pack2(const float* __restrict__ w2ih, const float* __restrict__ w2hh,
                        float* __restrict__ Wc2) {
  int idx = blockIdx.x * 256 + threadIdx.x;     // 384*256
  int o = idx & 255, k = idx >> 8;
  Wc2[idx] = (k < 128) ? w2ih[o * 128 + k] : w2hh[o * 256 + (k - 128)];
}

__global__ void k_copy4(const f4v* __restrict__ in, f4v* __restrict__ out, int n4) {
  int i = blockIdx.x * 256 + threadIdx.x;
  if (i < n4) {
    f4v v = __builtin_nontemporal_load(in + i);
    out[i] = v;                      // regular store: L2 write-combining
  }
}

// ---------------- pre_att = enc @ W1^T + b1 ----------------
#define NR 20
__global__ __launch_bounds__(256) void k_pre(const float* __restrict__ enc,
                                             const float* __restrict__ W1T,
                                             const float* __restrict__ ab1,
                                             float* __restrict__ pre) {
  const int b = blockIdx.y, n0 = blockIdx.x * NR, tid = threadIdx.x;
  __shared__ __align__(16) float es[NR * JDN];
  for (int r = 0; r < NR; ++r)
    es[r * JDN + tid] = enc[((size_t)(b * NN + n0 + r)) * JDN + tid];
  __syncthreads();
  float acc[NR];
#pragma unroll
  for (int r = 0; r < NR; ++r) acc[r] = 0.0f;
  const f4v* es4 = (const f4v*)es;
  for (int k0 = 0; k0 < JDN; k0 += 4) {
    float w0 = W1T[(k0 + 0) * AHN + tid];
    float w1 = W1T[(k0 + 1) * AHN + tid];
    float w2 = W1T[(k0 + 2) * AHN + tid];
    float w3 = W1T[(k0 + 3) * AHN + tid];
#pragma unroll
    for (int r = 0; r < NR; ++r) {
      f4v e = es4[r * 64 + (k0 >> 2)];
      acc[r] += e.x * w0 + e.y * w1 + e.z * w2 + e.w * w3;
    }
  }
  float bb = ab1[tid];
  for (int r = 0; r < NR; ++r)
    pre[((size_t)(b * NN + n0 + r)) * AHN + tid] = acc[r] + bb;
}

// ---------------- the full 200-step decode: one block per batch ----------------
// 512 threads. step1: Whh in regs, h1 double-buffered in LDS (1 barrier/m-step).
// fc/rnn2/q: K-split matvecs with 8-acc unrolled load streams (L2-resident weights).
// scores: NT loads on pre (streaming, evict-first) + depth-2 register pipeline.
__global__ __launch_bounds__(512, 4) void k_decode(
    const float* __restrict__ pt, const float* __restrict__ nm,
    const float* __restrict__ w1ih, const float* __restrict__ b1,
    const float* __restrict__ whh,
    const float* __restrict__ mw, const float* __restrict__ mb,
    const float* __restrict__ fcWT, const float* __restrict__ fcb,
    const float* __restrict__ d0h,
    const float* __restrict__ Wc2, const float* __restrict__ b2,
    const float* __restrict__ attW2T, const float* __restrict__ ab2,
    const float* __restrict__ attv,
    const float* __restrict__ pre,
    float* __restrict__ out_idx, float* __restrict__ out_logp) {
  const int b = blockIdx.x, tid = threadIdx.x;
  const int w = tid >> 6, l = tid & 63;

  // hm: [0..144)=h1 bufA (4 chunks of 32 @ stride 36), [144..288)=h1 bufB,
  //     [288..320)=m_emb
  __shared__ __align__(16) float hm[320];
  __shared__ __align__(16) float u[384];     // [0:128)=di, [128:384)=h2
  __shared__ float qs[256];
  __shared__ float ms[256];
  __shared__ float partial[512];
  __shared__ float Ps[40];
  __shared__ float wredv[8]; __shared__ int wredi[8];
  __shared__ float wmax[8];  __shared__ float wsum[8];
  __shared__ int   schosen;  __shared__ float smax, ssum;

  // ---- init ----
  const int j = (w << 4) + (l & 15);   // step1 output index 0..127
  const int ks = l >> 4;               // step1 K-chunk 0..3
  float wr[32];
  {
    const float* wp = whh + j * H1N + ks * 32;
#pragma unroll
    for (int i = 0; i < 32; i += 4) {
      f4v t4 = *(const f4v*)(wp + i);
      wr[i] = t4.x; wr[i + 1] = t4.y; wr[i + 2] = t4.z; wr[i + 3] = t4.w;
    }
  }
  const float w1a = w1ih[2 * j], w1b = w1ih[2 * j + 1], b1j = b1[j];
  const float v0 = attv[l], v1 = attv[l + 64], v2 = attv[l + 128], v3 = attv[l + 192];
  const float fcb_r = (tid < 128) ? fcb[tid] : 0.0f;
  const float b2_r  = (tid < 256) ? b2[tid]  : 0.0f;
  const float ab2_r = (tid < 256) ? ab2[tid] : 0.0f;
  int avail_r = 1;

  if (tid < 256) u[128 + tid] = d0h[tid];
  if (tid < 32)  hm[288 + tid] = nm[b] * mw[tid] + mb[tid];
  if (tid >= 64 && tid < 192) {                     // zero h1 bufA
    int p = tid - 64;
    hm[(p >> 5) * 36 + (p & 31)] = 0.0f;
  }
  if (tid < 40) Ps[tid] = 0.0f;
  __syncthreads();

  for (int t = 0; t < TT; ++t) {
    uint32_t sk0, sk1; tf2x32(0u, 42u, 0u, (uint32_t)t, sk0, sk1);

    // ---- step1: RNN over 20 machines (1 barrier per step) ----
    for (int m = 0; m < MM; ++m) {
      float x0 = Ps[2 * m], x1 = Ps[2 * m + 1];
      float acc = 0.0f;
      const f4v* hm4 = (const f4v*)(hm + (m & 1) * 144 + ks * 36);
#pragma unroll
      for (int i = 0; i < 8; ++i) {
        f4v hv = hm4[i];
        acc += wr[4 * i] * hv.x;     acc += wr[4 * i + 1] * hv.y;
        acc += wr[4 * i + 2] * hv.z; acc += wr[4 * i + 3] * hv.w;
      }
      acc += __shfl_xor(acc, 16);
      acc += __shfl_xor(acc, 32);
      if (ks == 0) {
        float hv = tanhf(acc + x0 * w1a + x1 * w1b + b1j);
        hm[(1 - (m & 1)) * 144 + (j >> 5) * 36 + (j & 31)] = hv;
      }
      __syncthreads();
    }
    // final h1 is in bufA (hm[0..144))

    // ---- fc: di = [hT, m_emb] @ fcW^T + fcb ; K=160 split x4 ----
    {
      const int ksf = tid >> 7, o = tid & 127, k0 = ksf * 40;
      float a0=0,a1=0,a2=0,a3=0,a4=0,a5=0,a6=0,a7=0;
#pragma unroll
      for (int i0 = 0; i0 < 40; i0 += 8) {
#pragma unroll
        for (int q8 = 0; q8 < 8; ++q8) {
          int k = k0 + i0 + q8;
          float hv = (k < 128) ? hm[(k >> 5) * 36 + (k & 31)] : hm[288 + (k - 128)];
          float wv = fcWT[k * 128 + o];
          if (q8 == 0) a0 += hv * wv; else if (q8 == 1) a1 += hv * wv;
          else if (q8 == 2) a2 += hv * wv; else if (q8 == 3) a3 += hv * wv;
          else if (q8 == 4) a4 += hv * wv; else if (q8 == 5) a5 += hv * wv;
          else if (q8 == 6) a6 += hv * wv; else a7 += hv * wv;
        }
      }
      partial[tid] = ((a0 + a1) + (a2 + a3)) + ((a4 + a5) + (a6 + a7));
      __syncthreads();
      if (tid < 128)
        u[tid] = partial[tid] + partial[128 + tid] + partial[256 + tid] +
                 partial[384 + tid] + fcb_r;
      __syncthreads();
    }

    // ---- rnn2: h2n = tanh([di,h2] @ Wc2 + b2) ; K=384 split x2 ----
    {
      const int ks2 = tid >> 8, o2 = tid & 255, kb = ks2 * 192;
      float a0=0,a1=0,a2=0,a3=0,a4=0,a5=0,a6=0,a7=0;
      const f4v* u4 = (const f4v*)u;
#pragma unroll
      for (int i0 = 0; i0 < 192; i0 += 8) {
        f4v ua = u4[(kb + i0) >> 2];
        f4v ub = u4[((kb + i0) >> 2) + 1];
        const float* Wp = Wc2 + (size_t)(kb + i0) * 256 + o2;
        a0 += ua.x * Wp[0];    a1 += ua.y * Wp[256];
        a2 += ua.z * Wp[512];  a3 += ua.w * Wp[768];
        a4 += ub.x * Wp[1024]; a5 += ub.y * Wp[1280];
        a6 += ub.z * Wp[1536]; a7 += ub.w * Wp[1792];
      }
      partial[tid] = ((a0 + a1) + (a2 + a3)) + ((a4 + a5) + (a6 + a7));
      __syncthreads();
      if (tid < 256)
        u[128 + tid] = tanhf((partial[tid] + partial[256 + tid]) + b2_r);
      __syncthreads();
    }

    // ---- q = h2n @ attW2^T + ab2 ; K=256 split x2 ----
    {
      const int ksq = tid >> 8, oq = tid & 255, kq = ksq * 128;
      float a0=0,a1=0,a2=0,a3=0,a4=0,a5=0,a6=0,a7=0;
      const f4v* u4 = (const f4v*)u;
#pragma unroll
      for (int i0 = 0; i0 < 128; i0 += 8) {
        f4v ua = u4[(128 + kq + i0) >> 2];
        f4v ub = u4[((128 + kq + i0) >> 2) + 1];
        const float* Wp = attW2T + (size_t)(kq + i0) * 256 + oq;
        a0 += ua.x * Wp[0];    a1 += ua.y * Wp[256];
        a2 += ua.z * Wp[512];  a3 += ua.w * Wp[768];
        a4 += ub.x * Wp[1024]; a5 += ub.y * Wp[1280];
        a6 += ub.z * Wp[1536]; a7 += ub.w * Wp[1792];
      }
      partial[tid] = ((a0 + a1) + (a2 + a3)) + ((a4 + a5) + (a6 + a7));
      __syncthreads();
      if (tid < 256)
        qs[tid] = (partial[tid] + partial[256 + tid]) + ab2_r;
      __syncthreads();
    }

    // ---- scores: 8 waves x 25 rows; NT loads + depth-2 pipeline ----
    {
      const float q0 = qs[l], q1 = qs[l + 64], q2 = qs[l + 128], q3 = qs[l + 192];
      const float* prow = pre + ((size_t)(b * NN + w * 25)) * AHN;
      float ra0, ra1, ra2, ra3, rb0, rb1, rb2, rb3;
      ra0 = __builtin_nontemporal_load(prow + l);
      ra1 = __builtin_nontemporal_load(prow + l + 64);
      ra2 = __builtin_nontemporal_load(prow + l + 128);
      ra3 = __builtin_nontemporal_load(prow + l + 192);
      rb0 = __builtin_nontemporal_load(prow + AHN + l);
      rb1 = __builtin_nontemporal_load(prow + AHN + l + 64);
      rb2 = __builtin_nontemporal_load(prow + AHN + l + 128);
      rb3 = __builtin_nontemporal_load(prow + AHN + l + 192);
#pragma unroll
      for (int i = 0; i < 25; ++i) {
        float c0, c1, c2, c3;
        if ((i & 1) == 0) { c0 = ra0; c1 = ra1; c2 = ra2; c3 = ra3; }
        else              { c0 = rb0; c1 = rb1; c2 = rb2; c3 = rb3; }
        if (i + 2 < 25) {
          const float* np = prow + (size_t)(i + 2) * AHN;
          if ((i & 1) == 0) {
            ra0 = __builtin_nontemporal_load(np + l);
            ra1 = __builtin_nontemporal_load(np + l + 64);
            ra2 = __builtin_nontemporal_load(np + l + 128);
            ra3 = __builtin_nontemporal_load(np + l + 192);
          } else {
            rb0 = __builtin_nontemporal_load(np + l);
            rb1 = __builtin_nontemporal_load(np + l + 64);
            rb2 = __builtin_nontemporal_load(np + l + 128);
            rb3 = __builtin_nontemporal_load(np + l + 192);
          }
        }
        float s0 = tanhf(c0 + q0) * v0;
        float s1 = tanhf(c1 + q1) * v1;
        float s2 = tanhf(c2 + q2) * v2;
        float s3 = tanhf(c3 + q3) * v3;
        float s = (s0 + s1) + (s2 + s3);
#pragma unroll
        for (int d = 32; d > 0; d >>= 1) s += __shfl_down(s, d);
        if (l == 0) ms[w * 25 + i] = s;
      }
      __syncthreads();
    }

    // ---- gumbel + argmax + softmax/logp + state update ----
    {
      float masked = -INFINITY, z = -INFINITY; int zi = 256;
      if (tid < NN) {
        masked = avail_r ? ms[tid] : -1e9f;
        uint32_t o0, o1; tf2x32(sk0, sk1, 0u, (uint32_t)(b * NN + tid), o0, o1);
        uint32_t bits = o0 ^ o1;
        float f = __uint_as_float((bits >> 9) | 0x3f800000u) - 1.0f;
        const float TINY = 1.1754943508222875e-38f;
        f = f * (1.0f - TINY) + TINY;
        float g = -logf(-logf(fmaxf(f, TINY)));
        z = g + masked;
        zi = tid;
      }
      float rv = z; int ri = zi; float rm = masked;
#pragma unroll
      for (int d = 32; d > 0; d >>= 1) {
        float ov = __shfl_down(rv, d); int oi = __shfl_down(ri, d);
        float om = __shfl_down(rm, d);
        if (ov > rv || (ov == rv && oi < ri)) { rv = ov; ri = oi; }
        rm = fmaxf(rm, om);
      }
      if (l == 0) { wredv[w] = rv; wredi[w] = ri; wmax[w] = rm; }
      __syncthreads();
      if (tid == 0) {
        float bv = wredv[0]; int bi = wredi[0]; float bm = wmax[0];
        for (int k = 1; k < 8; ++k) {
          float ov = wredv[k]; int oi = wredi[k];
          if (ov > bv || (ov == bv && oi < bi)) { bv = ov; bi = oi; }
          bm = fmaxf(bm, wmax[k]);
        }
        schosen = bi; smax = bm;
      }
      __syncthreads();
      const int chosen = schosen; const float maxm = smax;
      // issue P_next gather early; latency hides under softmax
      float psv = 0.0f;
      if (tid < 40) psv = pt[((size_t)(b * NN + chosen)) * (MM * 2) + tid];
      if (tid == chosen) avail_r = 0;
      float ev = (tid < NN) ? expf(masked - maxm) : 0.0f;
      float sv = ev;
#pragma unroll
      for (int d = 32; d > 0; d >>= 1) sv += __shfl_down(sv, d);
      if (l == 0) wsum[w] = sv;
      __syncthreads();
      if (tid == 0)
        ssum = ((wsum[0] + wsum[1]) + (wsum[2] + wsum[3])) +
               ((wsum[4] + wsum[5]) + (wsum[6] + wsum[7]));
      __syncthreads();
      const float den = ssum;
      if (tid < NN)
        out_logp[((size_t)(b * TT + t)) * NN + tid] = logf(ev / den + 1e-9f);
      if (tid >= 256 && tid < 384) {                 // zero h1 bufA for next step
        int p = tid - 256;
        hm[(p >> 5) * 36 + (p & 31)] = 0.0f;
      }
      if (tid == 0) out_idx[b * TT + t] = (float)chosen;
      if (tid < 40) Ps[tid] = psv;
      __syncthreads();
    }
  }
}

extern "C" void kernel_launch(void* const* d_in, const int* in_sizes, int n_in,
                              void* d_out, int out_size, void* d_ws, size_t ws_size,
                              hipStream_t stream) {
  const float* enc  = (const float*)d_in[0];
  const float* pt   = (const float*)d_in[1];
  const float* nm   = (const float*)d_in[2];
  const float* w1ih = (const float*)d_in[3];
  const float* whh1 = (const float*)d_in[4];
  const float* b1   = (const float*)d_in[5];
  const float* mw   = (const float*)d_in[6];
  const float* mb   = (const float*)d_in[7];
  const float* fcW  = (const float*)d_in[8];
  const float* fcb  = (const float*)d_in[9];
  const float* d0h  = (const float*)d_in[10];
  const float* w2ih = (const float*)d_in[11];
  const float* w2hh = (const float*)d_in[12];
  const float* b2   = (const float*)d_in[13];
  const float* aw1  = (const float*)d_in[14];
  const float* ab1  = (const float*)d_in[15];
  const float* aw2  = (const float*)d_in[16];
  const float* ab2  = (const float*)d_in[17];
  const float* av   = (const float*)d_in[18];

  float* out      = (float*)d_out;
  float* out_idx  = out;                              // [512,200]
  float* out_logp = out + 102400;                     // [512,200,200]
  float* out_enc  = out + 102400 + 20480000;          // [512,200,256] (pre scratch)
  float* pre      = out_enc;

  float* ws     = (float*)d_ws;
  float* W1T    = ws;                 // 65536
  float* fcWT   = ws + 65536;         // 20480  [160][128]
  float* attW2T = ws + 86016;         // 65536  [256][256]
  float* Wc2    = ws + 151552;        // 98304  [384][256]

  k_transpose<<<(65536 + 255) / 256, 256, 0, stream>>>(aw1, W1T,    256, 256);
  k_transpose<<<(20480 + 255) / 256, 256, 0, stream>>>(fcW, fcWT,   128, 160);
  k_transpose<<<(65536 + 255) / 256, 256, 0, stream>>>(aw2, attW2T, 256, 256);
  k_pack2<<<384, 256, 0, stream>>>(w2ih, w2hh, Wc2);

  dim3 gpre(NN / NR, BB);
  k_pre<<<gpre, 256, 0, stream>>>(enc, W1T, ab1, pre);

  k_decode<<<BB, 512, 0, stream>>>(pt, nm, w1ih, b1, whh1, mw, mb, fcWT, fcb,
                                   d0h, Wc2, b2, attW2T, ab2, av,
                                   pre, out_idx, out_logp);

  k_copy4<<<(6553600 + 255) / 256, 256, 0, stream>>>((const f4v*)enc,
                                                     (f4v*)out_enc, 6553600);
}

// Round 4
// 24845.320 us; speedup vs baseline: 1.7363x; 1.7363x over previous
//
#include <hip/hip_runtime.h>
#include <hip/hip_bf16.h>
#include <stdint.h>

#define BB 512
#define NN 200
#define TT 200
#define MM 20
#define H1N 128
#define MEN 32
#define DIN 128
#define H2N 256
#define JDN 256
#define AHN 256

typedef float f4v __attribute__((ext_vector_type(4)));

// ---------------- threefry2x32 (JAX-exact) ----------------
__device__ __forceinline__ void tf2x32(uint32_t k0, uint32_t k1,
                                       uint32_t x0, uint32_t x1,
                                       uint32_t& o0, uint32_t& o1) {
  uint32_t ks2 = k0 ^ k1 ^ 0x1BD11BDAu;
  x0 += k0; x1 += k1;
#define TF_RND(R) { x0 += x1; x1 = (x1 << (R)) | (x1 >> (32 - (R))); x1 ^= x0; }
  TF_RND(13) TF_RND(15) TF_RND(26) TF_RND(6)   x0 += k1;  x1 += ks2 + 1u;
  TF_RND(17) TF_RND(29) TF_RND(16) TF_RND(24)  x0 += ks2; x1 += k0 + 2u;
  TF_RND(13) TF_RND(15) TF_RND(26) TF_RND(6)   x0 += k0;  x1 += k1 + 3u;
  TF_RND(17) TF_RND(29) TF_RND(16) TF_RND(24)  x0 += k1;  x1 += ks2 + 4u;
  TF_RND(13) TF_RND(15) TF_RND(26) TF_RND(6)   x0 += ks2; x1 += k0 + 5u;
#undef TF_RND
  o0 = x0; o1 = x1;
}

// ---------------- small utility kernels ----------------
__global__ void k_transpose(const float* __restrict__ in, float* __restrict__ out,
                            int R, int C) {
  int idx = blockIdx.x * 256 + threadIdx.x;
  if (idx < R * C) { int r = idx / C, c = idx - r * C; out[c * R + r] = in[idx]; }
}

// Wc2[k*256+o]: k<128 -> w2ih[o*128+k]; k>=128 -> w2hh[o*256+(k-128)]
__global__ void k_pack2(const float* __restrict__ w2ih, const float* __restrict__ w2hh,
                        float* __restrict__ Wc2) {
  int idx = blockIdx.x * 256 + threadIdx.x;     // 384*256
  int o = idx & 255, k = idx >> 8;
  Wc2[idx] = (k < 128) ? w2ih[o * 128 + k] : w2hh[o * 256 + (k - 128)];
}

__global__ void k_copy4(const f4v* __restrict__ in, f4v* __restrict__ out, int n4) {
  int i = blockIdx.x * 256 + threadIdx.x;
  if (i < n4) out[i] = in[i];
}

// ---------------- pre_att = enc @ W1^T + b1 ----------------
#define NR 20
__global__ __launch_bounds__(256) void k_pre(const float* __restrict__ enc,
                                             const float* __restrict__ W1T,
                                             const float* __restrict__ ab1,
                                             float* __restrict__ pre) {
  const int b = blockIdx.y, n0 = blockIdx.x * NR, tid = threadIdx.x;
  __shared__ __align__(16) float es[NR * JDN];
  for (int r = 0; r < NR; ++r)
    es[r * JDN + tid] = enc[((size_t)(b * NN + n0 + r)) * JDN + tid];
  __syncthreads();
  float acc[NR];
#pragma unroll
  for (int r = 0; r < NR; ++r) acc[r] = 0.0f;
  const f4v* es4 = (const f4v*)es;
  for (int k0 = 0; k0 < JDN; k0 += 4) {
    float w0 = W1T[(k0 + 0) * AHN + tid];
    float w1 = W1T[(k0 + 1) * AHN + tid];
    float w2 = W1T[(k0 + 2) * AHN + tid];
    float w3 = W1T[(k0 + 3) * AHN + tid];
#pragma unroll
    for (int r = 0; r < NR; ++r) {
      f4v e = es4[r * 64 + (k0 >> 2)];
      acc[r] += e.x * w0 + e.y * w1 + e.z * w2 + e.w * w3;
    }
  }
  float bb = ab1[tid];
  for (int r = 0; r < NR; ++r)
    pre[((size_t)(b * NN + n0 + r)) * AHN + tid] = acc[r] + bb;
}

// ---------------- di table: step1 RNN + fc for all (b, n) ----------------
// chain = b*201 + n; n==200 is the zero-P initial state. Reuses the verified
// round-2 step1/fc code (Whh slice in regs, h1 double-buffered in LDS).
__global__ __launch_bounds__(512) void k_di(
    const float* __restrict__ pt, const float* __restrict__ nm,
    const float* __restrict__ w1ih, const float* __restrict__ b1,
    const float* __restrict__ whh,
    const float* __restrict__ mw, const float* __restrict__ mb,
    const float* __restrict__ fcWT, const float* __restrict__ fcb,
    float* __restrict__ diOut) {
  const int chain = blockIdx.x;
  const int b = chain / 201, n = chain - b * 201;
  const int tid = threadIdx.x;
  const int w = tid >> 6, l = tid & 63;

  __shared__ __align__(16) float hm[320];   // 2x h1 (stride-36 chunks) + m_emb
  __shared__ float Ps[40];
  __shared__ float partial[512];

  const int j = (w << 4) + (l & 15);
  const int ks = l >> 4;
  float wr[32];
  {
    const float* wp = whh + j * H1N + ks * 32;
#pragma unroll
    for (int i = 0; i < 32; i += 4) {
      f4v t4 = *(const f4v*)(wp + i);
      wr[i] = t4.x; wr[i + 1] = t4.y; wr[i + 2] = t4.z; wr[i + 3] = t4.w;
    }
  }
  const float w1a = w1ih[2 * j], w1b = w1ih[2 * j + 1], b1j = b1[j];
  const float fcb_r = (tid < 128) ? fcb[tid] : 0.0f;

  if (tid < 32)  hm[288 + tid] = nm[b] * mw[tid] + mb[tid];
  if (tid >= 64 && tid < 192) {
    int p = tid - 64;
    hm[(p >> 5) * 36 + (p & 31)] = 0.0f;
  }
  if (tid < 40)
    Ps[tid] = (n < NN) ? pt[((size_t)(b * NN + n)) * (MM * 2) + tid] : 0.0f;
  __syncthreads();

  for (int m = 0; m < MM; ++m) {
    float x0 = Ps[2 * m], x1 = Ps[2 * m + 1];
    float acc = 0.0f;
    const f4v* hm4 = (const f4v*)(hm + (m & 1) * 144 + ks * 36);
#pragma unroll
    for (int i = 0; i < 8; ++i) {
      f4v hv = hm4[i];
      acc += wr[4 * i] * hv.x;     acc += wr[4 * i + 1] * hv.y;
      acc += wr[4 * i + 2] * hv.z; acc += wr[4 * i + 3] * hv.w;
    }
    acc += __shfl_xor(acc, 16);
    acc += __shfl_xor(acc, 32);
    if (ks == 0) {
      float hv = tanhf(acc + x0 * w1a + x1 * w1b + b1j);
      hm[(1 - (m & 1)) * 144 + (j >> 5) * 36 + (j & 31)] = hv;
    }
    __syncthreads();
  }

  // fc: di = [hT, m_emb] @ fcW^T + fcb ; K=160 split x4 (round-2 verbatim)
  {
    const int ksf = tid >> 7, o = tid & 127, k0 = ksf * 40;
    float a0=0,a1=0,a2=0,a3=0,a4=0,a5=0,a6=0,a7=0;
#pragma unroll
    for (int i0 = 0; i0 < 40; i0 += 8) {
#pragma unroll
      for (int q8 = 0; q8 < 8; ++q8) {
        int k = k0 + i0 + q8;
        float hv = (k < 128) ? hm[(k >> 5) * 36 + (k & 31)] : hm[288 + (k - 128)];
        float wv = fcWT[k * 128 + o];
        if (q8 == 0) a0 += hv * wv; else if (q8 == 1) a1 += hv * wv;
        else if (q8 == 2) a2 += hv * wv; else if (q8 == 3) a3 += hv * wv;
        else if (q8 == 4) a4 += hv * wv; else if (q8 == 5) a5 += hv * wv;
        else if (q8 == 6) a6 += hv * wv; else a7 += hv * wv;
      }
    }
    partial[tid] = ((a0 + a1) + (a2 + a3)) + ((a4 + a5) + (a6 + a7));
    __syncthreads();
    if (tid < 128)
      diOut[(size_t)chain * 128 + tid] =
          partial[tid] + partial[128 + tid] + partial[256 + tid] +
          partial[384 + tid] + fcb_r;
  }
}

// ---------------- per-call state init ----------------
__global__ void k_init(const float* __restrict__ d0h, const float* __restrict__ di,
                       float* __restrict__ diT, float* __restrict__ h2T0,
                       int* __restrict__ availI) {
  const int b = blockIdx.x, tid = threadIdx.x;
  if (tid < NN)  availI[b * NN + tid] = 1;
  h2T0[(size_t)tid * 512 + b] = d0h[tid];
  if (tid < 128)
    diT[(size_t)tid * 512 + b] = di[((size_t)(b * 201 + 200)) * 128 + tid];
}

// ---------------- kA: h2n^T = tanh(Wc2^T @ [diT; h2pT] + b2) ----------------
// grid 128 blocks x 512 thr; block owns outputs {2*bx, 2*bx+1}; weights are
// wave-uniform (scalar loads); state k-major [k][b] -> coalesced loads/stores.
__global__ __launch_bounds__(512) void kA(
    const float* __restrict__ diT, const float* __restrict__ h2pT,
    const float* __restrict__ Wc2, const float* __restrict__ b2,
    float* __restrict__ h2cT) {
  const int o0 = blockIdx.x * 2, b = threadIdx.x;
  float a0=0,a1=0,a2=0,a3=0, c0=0,c1=0,c2=0,c3=0;
  for (int k = 0; k < 128; k += 8) {
    float x0 = diT[(size_t)(k+0)*512+b], x1 = diT[(size_t)(k+1)*512+b];
    float x2 = diT[(size_t)(k+2)*512+b], x3 = diT[(size_t)(k+3)*512+b];
    float x4 = diT[(size_t)(k+4)*512+b], x5 = diT[(size_t)(k+5)*512+b];
    float x6 = diT[(size_t)(k+6)*512+b], x7 = diT[(size_t)(k+7)*512+b];
    const float* wp = Wc2 + (size_t)k * 256 + o0;
    a0 += x0*wp[0];    a1 += x1*wp[256];  a2 += x2*wp[512];  a3 += x3*wp[768];
    a0 += x4*wp[1024]; a1 += x5*wp[1280]; a2 += x6*wp[1536]; a3 += x7*wp[1792];
    c0 += x0*wp[1];    c1 += x1*wp[257];  c2 += x2*wp[513];  c3 += x3*wp[769];
    c0 += x4*wp[1025]; c1 += x5*wp[1281]; c2 += x6*wp[1537]; c3 += x7*wp[1793];
  }
  for (int k = 0; k < 256; k += 8) {
    float x0 = h2pT[(size_t)(k+0)*512+b], x1 = h2pT[(size_t)(k+1)*512+b];
    float x2 = h2pT[(size_t)(k+2)*512+b], x3 = h2pT[(size_t)(k+3)*512+b];
    float x4 = h2pT[(size_t)(k+4)*512+b], x5 = h2pT[(size_t)(k+5)*512+b];
    float x6 = h2pT[(size_t)(k+6)*512+b], x7 = h2pT[(size_t)(k+7)*512+b];
    const float* wp = Wc2 + (size_t)(128 + k) * 256 + o0;
    a0 += x0*wp[0];    a1 += x1*wp[256];  a2 += x2*wp[512];  a3 += x3*wp[768];
    a0 += x4*wp[1024]; a1 += x5*wp[1280]; a2 += x6*wp[1536]; a3 += x7*wp[1792];
    c0 += x0*wp[1];    c1 += x1*wp[257];  c2 += x2*wp[513];  c3 += x3*wp[769];
    c0 += x4*wp[1025]; c1 += x5*wp[1281]; c2 += x6*wp[1537]; c3 += x7*wp[1793];
  }
  float s0 = (a0 + a1) + (a2 + a3);
  float s1 = (c0 + c1) + (c2 + c3);
  h2cT[(size_t)o0 * 512 + b]       = tanhf(s0 + b2[o0]);
  h2cT[(size_t)(o0 + 1) * 512 + b] = tanhf(s1 + b2[o0 + 1]);
}

// ---------------- kB: q^T = attW2^T-GEMM(h2n^T) + ab2 ----------------
__global__ __launch_bounds__(512) void kB(
    const float* __restrict__ h2cT, const float* __restrict__ attW2T,
    const float* __restrict__ ab2, float* __restrict__ qT) {
  const int o0 = blockIdx.x * 2, b = threadIdx.x;
  float a0=0,a1=0,a2=0,a3=0, c0=0,c1=0,c2=0,c3=0;
  for (int k = 0; k < 256; k += 8) {
    float x0 = h2cT[(size_t)(k+0)*512+b], x1 = h2cT[(size_t)(k+1)*512+b];
    float x2 = h2cT[(size_t)(k+2)*512+b], x3 = h2cT[(size_t)(k+3)*512+b];
    float x4 = h2cT[(size_t)(k+4)*512+b], x5 = h2cT[(size_t)(k+5)*512+b];
    float x6 = h2cT[(size_t)(k+6)*512+b], x7 = h2cT[(size_t)(k+7)*512+b];
    const float* wp = attW2T + (size_t)k * 256 + o0;
    a0 += x0*wp[0];    a1 += x1*wp[256];  a2 += x2*wp[512];  a3 += x3*wp[768];
    a0 += x4*wp[1024]; a1 += x5*wp[1280]; a2 += x6*wp[1536]; a3 += x7*wp[1792];
    c0 += x0*wp[1];    c1 += x1*wp[257];  c2 += x2*wp[513];  c3 += x3*wp[769];
    c0 += x4*wp[1025]; c1 += x5*wp[1281]; c2 += x6*wp[1537]; c3 += x7*wp[1793];
  }
  float s0 = (a0 + a1) + (a2 + a3);
  float s1 = (c0 + c1) + (c2 + c3);
  qT[(size_t)o0 * 512 + b]       = s0 + ab2[o0];
  qT[(size_t)(o0 + 1) * 512 + b] = s1 + ab2[o0 + 1];
}

// ---------------- kC: scores + gumbel argmax + softmax/logp + state ----------------
__global__ __launch_bounds__(512) void kC(
    const float* __restrict__ pre, const float* __restrict__ attv,
    const float* __restrict__ qT, int* __restrict__ availI,
    const float* __restrict__ di, float* __restrict__ diT,
    float* __restrict__ out_idx, float* __restrict__ out_logp, int t) {
  const int b = blockIdx.x, tid = threadIdx.x;
  const int w = tid >> 6, l = tid & 63;
  __shared__ float qs[256];
  __shared__ float ms[256];
  __shared__ float wredv[8]; __shared__ int wredi[8];
  __shared__ float wmax[8];  __shared__ float wsum[8];
  __shared__ int   schosen;  __shared__ float smax, ssum;

  if (tid < 256) qs[tid] = qT[(size_t)tid * 512 + b];
  int av = 1;
  if (tid < NN) av = availI[b * NN + tid];
  uint32_t sk0, sk1; tf2x32(0u, 42u, 0u, (uint32_t)t, sk0, sk1);
  __syncthreads();

  const float v0 = attv[l], v1 = attv[l + 64], v2 = attv[l + 128], v3 = attv[l + 192];
  const float q0 = qs[l], q1 = qs[l + 64], q2 = qs[l + 128], q3 = qs[l + 192];

  // scores: 8 waves x 25 rows
  {
    const float* prow = pre + ((size_t)(b * NN + w * 25)) * AHN;
    for (int i = 0; i < 25; ++i) {
      float s0 = tanhf(prow[l]       + q0) * v0;
      float s1 = tanhf(prow[l + 64]  + q1) * v1;
      float s2 = tanhf(prow[l + 128] + q2) * v2;
      float s3 = tanhf(prow[l + 192] + q3) * v3;
      float s = (s0 + s1) + (s2 + s3);
#pragma unroll
      for (int d = 32; d > 0; d >>= 1) s += __shfl_down(s, d);
      if (l == 0) ms[w * 25 + i] = s;
      prow += AHN;
    }
    __syncthreads();
  }

  // gumbel + argmax + softmax/logp (round-2 verbatim math)
  float masked = -INFINITY, z = -INFINITY; int zi = 256;
  if (tid < NN) {
    masked = av ? ms[tid] : -1e9f;
    uint32_t o0, o1; tf2x32(sk0, sk1, 0u, (uint32_t)(b * NN + tid), o0, o1);
    uint32_t bits = o0 ^ o1;
    float f = __uint_as_float((bits >> 9) | 0x3f800000u) - 1.0f;
    const float TINY = 1.1754943508222875e-38f;
    f = f * (1.0f - TINY) + TINY;
    float g = -logf(-logf(fmaxf(f, TINY)));
    z = g + masked;
    zi = tid;
  }
  float rv = z; int ri = zi; float rm = masked;
#pragma unroll
  for (int d = 32; d > 0; d >>= 1) {
    float ov = __shfl_down(rv, d); int oi = __shfl_down(ri, d);
    float om = __shfl_down(rm, d);
    if (ov > rv || (ov == rv && oi < ri)) { rv = ov; ri = oi; }
    rm = fmaxf(rm, om);
  }
  if (l == 0) { wredv[w] = rv; wredi[w] = ri; wmax[w] = rm; }
  __syncthreads();
  if (tid == 0) {
    float bv = wredv[0]; int bi = wredi[0]; float bm = wmax[0];
    for (int k = 1; k < 8; ++k) {
      float ov = wredv[k]; int oi = wredi[k];
      if (ov > bv || (ov == bv && oi < bi)) { bv = ov; bi = oi; }
      bm = fmaxf(bm, wmax[k]);
    }
    schosen = bi; smax = bm;
  }
  __syncthreads();
  const int chosen = schosen; const float maxm = smax;
  // next-step diT column gather (replaces step1 in the loop)
  if (tid < 128)
    diT[(size_t)tid * 512 + b] = di[((size_t)(b * 201 + chosen)) * 128 + tid];
  if (tid == chosen) availI[b * NN + tid] = 0;
  float ev = (tid < NN) ? expf(masked - maxm) : 0.0f;
  float sv = ev;
#pragma unroll
  for (int d = 32; d > 0; d >>= 1) sv += __shfl_down(sv, d);
  if (l == 0) wsum[w] = sv;
  __syncthreads();
  if (tid == 0)
    ssum = ((wsum[0] + wsum[1]) + (wsum[2] + wsum[3])) +
           ((wsum[4] + wsum[5]) + (wsum[6] + wsum[7]));
  __syncthreads();
  const float den = ssum;
  if (tid < NN)
    out_logp[((size_t)(b * TT + t)) * NN + tid] = logf(ev / den + 1e-9f);
  if (tid == 0) out_idx[b * TT + t] = (float)chosen;
}

extern "C" void kernel_launch(void* const* d_in, const int* in_sizes, int n_in,
                              void* d_out, int out_size, void* d_ws, size_t ws_size,
                              hipStream_t stream) {
  const float* enc  = (const float*)d_in[0];
  const float* pt   = (const float*)d_in[1];
  const float* nm   = (const float*)d_in[2];
  const float* w1ih = (const float*)d_in[3];
  const float* whh1 = (const float*)d_in[4];
  const float* b1   = (const float*)d_in[5];
  const float* mw   = (const float*)d_in[6];
  const float* mb   = (const float*)d_in[7];
  const float* fcW  = (const float*)d_in[8];
  const float* fcb  = (const float*)d_in[9];
  const float* d0h  = (const float*)d_in[10];
  const float* w2ih = (const float*)d_in[11];
  const float* w2hh = (const float*)d_in[12];
  const float* b2   = (const float*)d_in[13];
  const float* aw1  = (const float*)d_in[14];
  const float* ab1  = (const float*)d_in[15];
  const float* aw2  = (const float*)d_in[16];
  const float* ab2  = (const float*)d_in[17];
  const float* av   = (const float*)d_in[18];

  float* out      = (float*)d_out;
  float* out_idx  = out;                              // [512,200]
  float* out_logp = out + 102400;                     // [512,200,200]
  float* out_enc  = out + 102400 + 20480000;          // [512,200,256] (pre scratch)
  float* pre      = out_enc;

  float* ws     = (float*)d_ws;
  float* W1T    = ws;                       // 65536
  float* fcWT   = ws + 65536;               // 20480   [160][128]
  float* attW2T = ws + 86016;               // 65536   [256][256] k-major
  float* Wc2    = ws + 151552;              // 98304   [384][256] k-major
  float* diT    = ws + 249856;              // 65536   [128][512]
  float* h2T0   = ws + 315392;              // 131072  [256][512]
  float* h2T1   = ws + 446464;              // 131072
  float* qT     = ws + 577536;              // 131072  [256][512]
  int*   availI = (int*)(ws + 708608);      // 102400
  float* di     = ws + 811008;              // 13172736 [512*201][128]
  float* h2T[2] = { h2T0, h2T1 };

  k_transpose<<<(65536 + 255) / 256, 256, 0, stream>>>(aw1, W1T,    256, 256);
  k_transpose<<<(20480 + 255) / 256, 256, 0, stream>>>(fcW, fcWT,   128, 160);
  k_transpose<<<(65536 + 255) / 256, 256, 0, stream>>>(aw2, attW2T, 256, 256);
  k_pack2<<<384, 256, 0, stream>>>(w2ih, w2hh, Wc2);

  dim3 gpre(NN / NR, BB);
  k_pre<<<gpre, 256, 0, stream>>>(enc, W1T, ab1, pre);

  k_di<<<BB * 201, 512, 0, stream>>>(pt, nm, w1ih, b1, whh1, mw, mb, fcWT, fcb, di);
  k_init<<<BB, 256, 0, stream>>>(d0h, di, diT, h2T0, availI);

  for (int t = 0; t < TT; ++t) {
    kA<<<128, 512, 0, stream>>>(diT, h2T[t & 1], Wc2, b2, h2T[(t + 1) & 1]);
    kB<<<128, 512, 0, stream>>>(h2T[(t + 1) & 1], attW2T, ab2, qT);
    kC<<<BB, 512, 0, stream>>>(pre, av, qT, availI, di, diT,
                               out_idx, out_logp, t);
  }

  k_copy4<<<(6553600 + 255) / 256, 256, 0, stream>>>((const f4v*)enc,
                                                     (f4v*)out_enc, 6553600);
}